// Round 6
// baseline (121.518 us; speedup 1.0000x reference)
//
#include <hip/hip_runtime.h>
#include <hip/hip_bf16.h>

#define N_NODES 50000
#define NLAT 10
#define MU 32
#define BATCH 8
#define CHUNK 2000
#define NCHUNK 25
#define ENC_BLOCKS (BATCH * NLAT * NCHUNK)     // 2000
#define TR_BLOCKS ((N_NODES + 255) / 256)      // 196
#define DT_STRIDE 16        // floats per node in transposed decoder (64B line)
#define NPB 64              // nodes per main-kernel block

typedef float v2f __attribute__((ext_vector_type(2)));

static __device__ __forceinline__ v2f v2_fma(v2f a, v2f b, v2f c) {
#if __has_builtin(__builtin_elementwise_fma)
    return __builtin_elementwise_fma(a, b, c);
#else
    v2f r; r[0] = fmaf(a[0], b[0], c[0]); r[1] = fmaf(a[1], b[1], c[1]); return r;
#endif
}
static __device__ __forceinline__ v2f v2_max0(v2f a) {
#if __has_builtin(__builtin_elementwise_max)
    v2f z = {0.0f, 0.0f};
    return __builtin_elementwise_max(a, z);
#else
    v2f r; r[0] = fmaxf(a[0], 0.0f); r[1] = fmaxf(a[1], 0.0f); return r;
#endif
}

// ---------------- Kernel 1: encode partials (blocks 0..1999) + decoder
// transpose (blocks 2000..2195).
__global__ __launch_bounds__(256) void encode_a_transpose(
    const float* __restrict__ x, const float* __restrict__ enc_w,
    const float* __restrict__ dec,
    float* __restrict__ partial, float* __restrict__ dec_t) {
    const int bid = blockIdx.x;
    if (bid < ENC_BLOCKS) {
        const int c  = bid % NCHUNK;
        const int bi = bid / NCHUNK;
        const int b = bi / NLAT, i = bi % NLAT;
        const float4* xr = (const float4*)(x + (size_t)b * N_NODES + c * CHUNK);
        const float4* wr = (const float4*)(enc_w + (size_t)i * N_NODES + c * CHUNK);
        float part = 0.0f;
        for (int q = threadIdx.x; q < CHUNK / 4; q += 256) {
            float4 xv = xr[q], wv = wr[q];
            part += xv.x * wv.x + xv.y * wv.y + xv.z * wv.z + xv.w * wv.w;
        }
        for (int off = 32; off; off >>= 1) part += __shfl_down(part, off, 64);
        __shared__ float s[4];
        if ((threadIdx.x & 63) == 0) s[threadIdx.x >> 6] = part;
        __syncthreads();
        if (threadIdx.x == 0) partial[bid] = (s[0] + s[1]) + (s[2] + s[3]);
    } else {
        const int p = (bid - ENC_BLOCKS) * 256 + threadIdx.x;
        if (p >= N_NODES) return;
        float v[DT_STRIDE];
        #pragma unroll
        for (int i = 0; i < NLAT; ++i) v[i] = dec[(size_t)i * N_NODES + p];
        #pragma unroll
        for (int i = NLAT; i < DT_STRIDE; ++i) v[i] = 0.0f;
        float4* dst = (float4*)(dec_t + (size_t)p * DT_STRIDE);
        #pragma unroll
        for (int q = 0; q < 4; ++q)
            dst[q] = make_float4(v[4*q], v[4*q+1], v[4*q+2], v[4*q+3]);
    }
}

// ---------------- Kernel 2: fused main. Block = 64 nodes, 320 threads
// (5 waves; wave g owns latent pair {2g, 2g+1}, lane = node).
// Phase 1: coalesced bw loads -> inv[b,i,node] in LDS (pairs over b).
// Phase 2: per (m, i-pair, node) ONE 8B dec_t gather (no batch duplication),
//          window math as packed-f32 pairs over b (v_pk_fma_f32 rate).
// Phase 3: LDS reduction over i, coalesced store.
__global__ __launch_bounds__(320) void nrbs_main_kernel(
    const float* __restrict__ dec_t,    // [N, 16]
    const float* __restrict__ bw,       // [n, n, N]
    const int*   __restrict__ nbr,      // [N, MU]
    const float* __restrict__ partial,  // [B*n, NCHUNK]
    const float* __restrict__ enc_b,    // [n]
    float*       __restrict__ out) {    // [B, N]
    __shared__ float s_enc[BATCH * NLAT];
    __shared__ float s_inv[NLAT][4][NPB][2];     // [i][b/2][node][b&1] 20.5 KB
    __shared__ int   s_nbr[NPB][MU + 1];         // padded: conflict-free 8.4 KB
    __shared__ int   s_tm[NPB];
    __shared__ float s_red[NLAT][BATCH][NPB];    // 20.5 KB
    const int tid   = threadIdx.x;
    const int node0 = blockIdx.x * NPB;

    // prologue: finish encode reduction; init tmax; stage neighbour lists
    if (tid < BATCH * NLAT) {
        float s = 0.0f;
        #pragma unroll
        for (int c = 0; c < NCHUNK; ++c) s += partial[tid * NCHUNK + c];
        s_enc[tid] = s + enc_b[tid % NLAT];
    }
    if (tid < NPB) s_tm[tid] = 0;
    for (int j = tid; j < NPB * MU / 4; j += 320) {   // 512 int4s
        const int node = j >> 3, ch = j & 7;
        int4 v = make_int4(0, 0, 0, 0);
        if (node0 + node < N_NODES)
            v = ((const int4*)(nbr + (size_t)(node0 + node) * MU))[ch];
        s_nbr[node][ch * 4 + 0] = v.x; s_nbr[node][ch * 4 + 1] = v.y;
        s_nbr[node][ch * 4 + 2] = v.z; s_nbr[node][ch * 4 + 3] = v.w;
    }
    __syncthreads();

    const int g  = tid >> 6;          // wave 0..4 -> latent pair
    const int nl = tid & 63;          // node within block
    const int i0 = 2 * g;
    const int p  = node0 + nl;
    const bool act = (p < N_NODES);

    // ---- Phase 1: z -> sigmoid -> inv = 1/(w*MU)^2, store pairs over b
    if (act) {
        float tloc = 0.0f;
        #pragma unroll
        for (int ii = 0; ii < 2; ++ii) {
            const int i = i0 + ii;
            float bwv[NLAT];
            #pragma unroll
            for (int k = 0; k < NLAT; ++k)
                bwv[k] = bw[((size_t)(i * NLAT + k)) * N_NODES + p];
            #pragma unroll
            for (int b = 0; b < BATCH; ++b) {
                float z = 0.0f;
                #pragma unroll
                for (int k = 0; k < NLAT; ++k)
                    z = fmaf(s_enc[b * NLAT + k], bwv[k], z);
                const float w = 1.0f / (1.0f + __expf(-z));
                const float t = w * (float)MU;
                tloc = fmaxf(tloc, t);
                s_inv[i][b >> 1][nl][b & 1] = __builtin_amdgcn_rcpf(t * t);
            }
        }
        atomicMax(&s_tm[nl], __float_as_int(tloc));   // t>0: float bits ordered
    }
    __syncthreads();

    // ---- Phase 2: windows, packed over b-pairs; one 8B gather per (m, i-pair)
    if (act) {
        v2f inv2[2][4], asum[2][4], ssum[2][4];
        #pragma unroll
        for (int ii = 0; ii < 2; ++ii)
            #pragma unroll
            for (int b2 = 0; b2 < 4; ++b2) {
                inv2[ii][b2] = *(const v2f*)&s_inv[i0 + ii][b2][nl][0];
                asum[ii][b2] = (v2f){0.0f, 0.0f};
                ssum[ii][b2] = (v2f){0.0f, 0.0f};
            }
        const int mcap = min(MU, (int)__int_as_float(s_tm[nl]) + 1);

        for (int m = 0; m < mcap; ++m) {
            const int idx = s_nbr[nl][m];
            const v2f g2 = *(const v2f*)(dec_t + (size_t)idx * DT_STRIDE + i0);
            const float m2 = (float)(m * m);
            const v2f nm2 = {-m2, -m2}, one = {1.0f, 1.0f};
            #pragma unroll
            for (int ii = 0; ii < 2; ++ii) {
                const v2f gb = {g2[ii], g2[ii]};
                #pragma unroll
                for (int b2 = 0; b2 < 4; ++b2) {
                    v2f win = v2_max0(v2_fma(nm2, inv2[ii][b2], one));
                    ssum[ii][b2] += win;
                    asum[ii][b2] = v2_fma(gb, win, asum[ii][b2]);
                }
            }
        }
        #pragma unroll
        for (int ii = 0; ii < 2; ++ii)
            #pragma unroll
            for (int b2 = 0; b2 < 4; ++b2)
                #pragma unroll
                for (int h = 0; h < 2; ++h) {
                    const int b = b2 * 2 + h;
                    s_red[i0 + ii][b][nl] =
                        s_enc[b * NLAT + i0 + ii] * asum[ii][b2][h] *
                        __builtin_amdgcn_rcpf(ssum[ii][b2][h]);
                }
    }
    __syncthreads();

    // ---- Phase 3: reduce over i, coalesced store
    if (tid < 256) {
        const int b = tid >> 5, q = tid & 31;
        #pragma unroll
        for (int h = 0; h < 2; ++h) {
            const int node = q + 32 * h, p2 = node0 + node;
            if (p2 < N_NODES) {
                float s = 0.0f;
                #pragma unroll
                for (int i = 0; i < NLAT; ++i) s += s_red[i][b][node];
                out[(size_t)b * N_NODES + p2] = s;
            }
        }
    }
}

extern "C" void kernel_launch(void* const* d_in, const int* in_sizes, int n_in,
                              void* d_out, int out_size, void* d_ws, size_t ws_size,
                              hipStream_t stream) {
    const float* x       = (const float*)d_in[0];   // [B, N]
    const float* enc_w   = (const float*)d_in[1];   // [n, N]
    const float* enc_b   = (const float*)d_in[2];   // [n]
    const float* decoder = (const float*)d_in[3];   // [n, N]
    const float* bwl     = (const float*)d_in[4];   // [n, n, N]
    const int*   nbr     = (const int*)d_in[5];     // [N, MU]
    float* out = (float*)d_out;                     // [B, N]

    float* partial = (float*)((char*)d_ws + 1024);   // 2000 floats
    float* dec_t   = (float*)((char*)d_ws + 65536);  // 3.2 MB

    encode_a_transpose<<<ENC_BLOCKS + TR_BLOCKS, 256, 0, stream>>>(
        x, enc_w, decoder, partial, dec_t);

    const int blocks = (N_NODES + NPB - 1) / NPB;   // 782
    nrbs_main_kernel<<<blocks, 320, 0, stream>>>(
        dec_t, bwl, nbr, partial, enc_b, out);
}

// Round 7
// 107.587 us; speedup vs baseline: 1.1295x; 1.1295x over previous
//
#include <hip/hip_runtime.h>
#include <hip/hip_bf16.h>

#define N_NODES 50000
#define NLAT 10
#define MU 32
#define BATCH 8
#define CHUNK 2000
#define NCHUNK 25
#define ENC_BLOCKS (BATCH * NLAT * NCHUNK)     // 2000
#define TR_BLOCKS ((N_NODES + 255) / 256)      // 196
#define DT_STRIDE 16        // floats per node in transposed decoder (64B line)
#define NPB 32              // nodes per main-kernel block

typedef float v2f __attribute__((ext_vector_type(2)));

static __device__ __forceinline__ v2f v2_fma(v2f a, v2f b, v2f c) {
#if __has_builtin(__builtin_elementwise_fma)
    return __builtin_elementwise_fma(a, b, c);
#else
    v2f r; r[0] = fmaf(a[0], b[0], c[0]); r[1] = fmaf(a[1], b[1], c[1]); return r;
#endif
}
static __device__ __forceinline__ v2f v2_max0(v2f a) {
#if __has_builtin(__builtin_elementwise_max)
    v2f z = {0.0f, 0.0f};
    return __builtin_elementwise_max(a, z);
#else
    v2f r; r[0] = fmaxf(a[0], 0.0f); r[1] = fmaxf(a[1], 0.0f); return r;
#endif
}

// ---------------- Kernel 1: encode partials (blocks 0..1999) + decoder
// transpose (blocks 2000..2195). Unchanged from R5.
__global__ __launch_bounds__(256) void encode_a_transpose(
    const float* __restrict__ x, const float* __restrict__ enc_w,
    const float* __restrict__ dec,
    float* __restrict__ partial, float* __restrict__ dec_t) {
    const int bid = blockIdx.x;
    if (bid < ENC_BLOCKS) {
        const int c  = bid % NCHUNK;
        const int bi = bid / NCHUNK;
        const int b = bi / NLAT, i = bi % NLAT;
        const float4* xr = (const float4*)(x + (size_t)b * N_NODES + c * CHUNK);
        const float4* wr = (const float4*)(enc_w + (size_t)i * N_NODES + c * CHUNK);
        float part = 0.0f;
        for (int q = threadIdx.x; q < CHUNK / 4; q += 256) {
            float4 xv = xr[q], wv = wr[q];
            part += xv.x * wv.x + xv.y * wv.y + xv.z * wv.z + xv.w * wv.w;
        }
        for (int off = 32; off; off >>= 1) part += __shfl_down(part, off, 64);
        __shared__ float s[4];
        if ((threadIdx.x & 63) == 0) s[threadIdx.x >> 6] = part;
        __syncthreads();
        if (threadIdx.x == 0) partial[bid] = (s[0] + s[1]) + (s[2] + s[3]);
    } else {
        const int p = (bid - ENC_BLOCKS) * 256 + threadIdx.x;
        if (p >= N_NODES) return;
        float v[DT_STRIDE];
        #pragma unroll
        for (int i = 0; i < NLAT; ++i) v[i] = dec[(size_t)i * N_NODES + p];
        #pragma unroll
        for (int i = NLAT; i < DT_STRIDE; ++i) v[i] = 0.0f;
        float4* dst = (float4*)(dec_t + (size_t)p * DT_STRIDE);
        #pragma unroll
        for (int q = 0; q < 4; ++q)
            dst[q] = make_float4(v[4*q], v[4*q+1], v[4*q+2], v[4*q+3]);
    }
}

// ---------------- Kernel 2: fused main. Block = 32 nodes, 512 threads.
// Phase A (wave w: i = w (+8 for upper half-wave, w<2); lane = node):
//   coalesced bw loads -> inv[b] & tmax -> LDS [i][node][b] (b128-friendly).
// Phase B (thread = (node, islot); wave = 4 nodes x 16 i-slots):
//   per m ONE scalar dec_t gather -> only 4 distinct lines per instruction
//   (the 10 active i-lanes of a node share one 64B dec_t line).
//   Window math packed over b-pairs.
// Epilogue: 16-wide shuffle butterfly reduces over i; lane islot==0 stores.
__global__ __launch_bounds__(512) void nrbs_main_kernel(
    const float* __restrict__ dec_t,    // [N, 16]
    const float* __restrict__ bw,       // [n, n, N]
    const int*   __restrict__ nbr,      // [N, MU]
    const float* __restrict__ partial,  // [B*n, NCHUNK]
    const float* __restrict__ enc_b,    // [n]
    float*       __restrict__ out) {    // [B, N]
    __shared__ float s_enc[BATCH * NLAT];
    __shared__ float s_inv[NLAT][NPB][BATCH];   // 10*32*8*4 = 10 KB
    __shared__ float s_tm[NLAT][NPB];           // 1.25 KB
    __shared__ int   s_nbr[NPB][MU + 1];        // 4.1 KB, padded
    const int tid   = threadIdx.x;
    const int node0 = blockIdx.x * NPB;

    // prologue: finish encode reduction; stage neighbour lists
    if (tid < BATCH * NLAT) {
        float s = 0.0f;
        #pragma unroll
        for (int c = 0; c < NCHUNK; ++c) s += partial[tid * NCHUNK + c];
        s_enc[tid] = s + enc_b[tid % NLAT];
    }
    {
        const int j = tid;                       // 256 int4 chunks, tid<256
        if (j < NPB * MU / 4) {
            const int node = j >> 3, ch = j & 7;
            int4 v = make_int4(0, 0, 0, 0);
            if (node0 + node < N_NODES)
                v = ((const int4*)(nbr + (size_t)(node0 + node) * MU))[ch];
            s_nbr[node][ch * 4 + 0] = v.x; s_nbr[node][ch * 4 + 1] = v.y;
            s_nbr[node][ch * 4 + 2] = v.z; s_nbr[node][ch * 4 + 3] = v.w;
        }
    }
    __syncthreads();

    // ---- Phase A: coalesced bw loads, inv/tmax -> LDS
    {
        const int w    = tid >> 6;
        const int lane = tid & 63;
        const int half = lane >> 5;
        const int node = lane & 31;
        const int i    = w + 8 * half;          // w<2 upper halves cover i=8,9
        const int p    = node0 + node;
        if (i < NLAT && p < N_NODES) {
            float bwv[NLAT];
            #pragma unroll
            for (int k = 0; k < NLAT; ++k)
                bwv[k] = bw[((size_t)(i * NLAT + k)) * N_NODES + p];
            float tloc = 0.0f;
            float invv[BATCH];
            #pragma unroll
            for (int b = 0; b < BATCH; ++b) {
                float z = 0.0f;
                #pragma unroll
                for (int k = 0; k < NLAT; ++k)
                    z = fmaf(s_enc[b * NLAT + k], bwv[k], z);
                const float sg = 1.0f / (1.0f + __expf(-z));
                const float t  = sg * (float)MU;
                tloc = fmaxf(tloc, t);
                invv[b] = __builtin_amdgcn_rcpf(t * t);
            }
            float4* dst = (float4*)&s_inv[i][node][0];
            dst[0] = make_float4(invv[0], invv[1], invv[2], invv[3]);
            dst[1] = make_float4(invv[4], invv[5], invv[6], invv[7]);
            s_tm[i][node] = tloc;
        }
    }
    __syncthreads();

    // ---- Phase B: thread = (node, islot)
    const int node  = tid >> 4;
    const int islot = tid & 15;
    const int p     = node0 + node;
    const bool act  = (islot < NLAT) && (p < N_NODES);

    v2f inv2[4], asum[4], ssum[4];
    #pragma unroll
    for (int b2 = 0; b2 < 4; ++b2) {
        inv2[b2] = (v2f){0.0f, 0.0f};
        asum[b2] = (v2f){0.0f, 0.0f};
        ssum[b2] = (v2f){0.0f, 0.0f};
    }
    int mcap = 0;
    if (act) {
        const float4* iv = (const float4*)&s_inv[islot][node][0];   // broadcast
        const float4 a = iv[0], c = iv[1];
        inv2[0] = (v2f){a.x, a.y}; inv2[1] = (v2f){a.z, a.w};
        inv2[2] = (v2f){c.x, c.y}; inv2[3] = (v2f){c.z, c.w};
        mcap = min(MU, (int)s_tm[islot][node] + 1);
    }

    for (int m = 0; m < mcap; ++m) {
        const int idx = s_nbr[node][m];                      // 4 addrs, broadcast
        const float g = dec_t[(size_t)idx * DT_STRIDE + islot]; // 4 lines/instr
        const float m2 = (float)(m * m);
        const v2f nm2 = {-m2, -m2}, one = {1.0f, 1.0f}, gg = {g, g};
        #pragma unroll
        for (int b2 = 0; b2 < 4; ++b2) {
            const v2f win = v2_max0(v2_fma(nm2, inv2[b2], one));
            ssum[b2] += win;
            asum[b2] = v2_fma(gg, win, asum[b2]);
        }
    }

    // epilogue: r[b] per (node,i), butterfly-sum over the 16-lane i group
    float r[BATCH];
    #pragma unroll
    for (int b2 = 0; b2 < 4; ++b2)
        #pragma unroll
        for (int h = 0; h < 2; ++h) {
            const int b = 2 * b2 + h;
            r[b] = act ? s_enc[b * NLAT + islot] * asum[b2][h] *
                         __builtin_amdgcn_rcpf(ssum[b2][h])
                       : 0.0f;
        }
    #pragma unroll
    for (int mask = 1; mask < 16; mask <<= 1)
        #pragma unroll
        for (int b = 0; b < BATCH; ++b)
            r[b] += __shfl_xor(r[b], mask, 16);

    if (islot == 0 && p < N_NODES) {
        #pragma unroll
        for (int b = 0; b < BATCH; ++b)
            out[(size_t)b * N_NODES + p] = r[b];
    }
}

extern "C" void kernel_launch(void* const* d_in, const int* in_sizes, int n_in,
                              void* d_out, int out_size, void* d_ws, size_t ws_size,
                              hipStream_t stream) {
    const float* x       = (const float*)d_in[0];   // [B, N]
    const float* enc_w   = (const float*)d_in[1];   // [n, N]
    const float* enc_b   = (const float*)d_in[2];   // [n]
    const float* decoder = (const float*)d_in[3];   // [n, N]
    const float* bwl     = (const float*)d_in[4];   // [n, n, N]
    const int*   nbr     = (const int*)d_in[5];     // [N, MU]
    float* out = (float*)d_out;                     // [B, N]

    float* partial = (float*)((char*)d_ws + 1024);   // 2000 floats
    float* dec_t   = (float*)((char*)d_ws + 65536);  // 3.2 MB

    encode_a_transpose<<<ENC_BLOCKS + TR_BLOCKS, 256, 0, stream>>>(
        x, enc_w, decoder, partial, dec_t);

    const int blocks = (N_NODES + NPB - 1) / NPB;   // 1563
    nrbs_main_kernel<<<blocks, 512, 0, stream>>>(
        dec_t, bwl, nbr, partial, enc_b, out);
}

// Round 8
// 107.338 us; speedup vs baseline: 1.1321x; 1.0023x over previous
//
#include <hip/hip_runtime.h>
#include <hip/hip_bf16.h>

#define N_NODES 50000
#define NLAT 10
#define MU 32
#define BATCH 8
#define CHUNK 2000
#define NCHUNK 25
#define ENC_BLOCKS (BATCH * NLAT * NCHUNK)     // 2000
#define TR_BLOCKS ((N_NODES + 255) / 256)      // 196
#define DT_STRIDE 16        // floats per node in transposed decoder (64B line)
#define NPB 64              // nodes per main-kernel block

typedef float v2f __attribute__((ext_vector_type(2)));

static __device__ __forceinline__ v2f v2_fma(v2f a, v2f b, v2f c) {
#if __has_builtin(__builtin_elementwise_fma)
    return __builtin_elementwise_fma(a, b, c);
#else
    v2f r; r[0] = fmaf(a[0], b[0], c[0]); r[1] = fmaf(a[1], b[1], c[1]); return r;
#endif
}
static __device__ __forceinline__ v2f v2_max0(v2f a) {
#if __has_builtin(__builtin_elementwise_max)
    v2f z = {0.0f, 0.0f};
    return __builtin_elementwise_max(a, z);
#else
    v2f r; r[0] = fmaxf(a[0], 0.0f); r[1] = fmaxf(a[1], 0.0f); return r;
#endif
}

// ---------------- Kernel 1: encode partials (blocks 0..1999) + decoder
// transpose (blocks 2000..2195). Unchanged.
__global__ __launch_bounds__(256) void encode_a_transpose(
    const float* __restrict__ x, const float* __restrict__ enc_w,
    const float* __restrict__ dec,
    float* __restrict__ partial, float* __restrict__ dec_t) {
    const int bid = blockIdx.x;
    if (bid < ENC_BLOCKS) {
        const int c  = bid % NCHUNK;
        const int bi = bid / NCHUNK;
        const int b = bi / NLAT, i = bi % NLAT;
        const float4* xr = (const float4*)(x + (size_t)b * N_NODES + c * CHUNK);
        const float4* wr = (const float4*)(enc_w + (size_t)i * N_NODES + c * CHUNK);
        float part = 0.0f;
        for (int q = threadIdx.x; q < CHUNK / 4; q += 256) {
            float4 xv = xr[q], wv = wr[q];
            part += xv.x * wv.x + xv.y * wv.y + xv.z * wv.z + xv.w * wv.w;
        }
        for (int off = 32; off; off >>= 1) part += __shfl_down(part, off, 64);
        __shared__ float s[4];
        if ((threadIdx.x & 63) == 0) s[threadIdx.x >> 6] = part;
        __syncthreads();
        if (threadIdx.x == 0) partial[bid] = (s[0] + s[1]) + (s[2] + s[3]);
    } else {
        const int p = (bid - ENC_BLOCKS) * 256 + threadIdx.x;
        if (p >= N_NODES) return;
        float v[DT_STRIDE];
        #pragma unroll
        for (int i = 0; i < NLAT; ++i) v[i] = dec[(size_t)i * N_NODES + p];
        #pragma unroll
        for (int i = NLAT; i < DT_STRIDE; ++i) v[i] = 0.0f;
        float4* dst = (float4*)(dec_t + (size_t)p * DT_STRIDE);
        #pragma unroll
        for (int q = 0; q < 4; ++q)
            dst[q] = make_float4(v[4*q], v[4*q+1], v[4*q+2], v[4*q+3]);
    }
}

// ---------------- Kernel 2: fused main. Block = 64 nodes, 512 threads.
// Phase A (wave g: i = g, g+8; lane = node 0..63): fully-coalesced bw loads,
//   inv[b] & tmax -> LDS.
// Phase B (thread = (node, ipair); wave = 8 nodes x 8 pairs, pairs 0..4
//   active covering i = {2q, 2q+1}): per m ONE float2 dec_t gather
//   (8 distinct 64B lines per wave-instr, 106K gather instrs total —
//   half of R7). Window math packed over b-pairs.
// Epilogue: width-8 butterfly -> every lane holds all 8 batch sums;
//   lane ipair stores batch ipair (coalesced 8-node runs).
__global__ __launch_bounds__(512) void nrbs_main_kernel(
    const float* __restrict__ dec_t,    // [N, 16]
    const float* __restrict__ bw,       // [n, n, N]
    const int*   __restrict__ nbr,      // [N, MU]
    const float* __restrict__ partial,  // [B*n, NCHUNK]
    const float* __restrict__ enc_b,    // [n]
    float*       __restrict__ out) {    // [B, N]
    __shared__ float s_enc[BATCH * NLAT];
    __shared__ float s_inv[NLAT][NPB][BATCH];   // 20 KB
    __shared__ int   s_tm[NPB];
    __shared__ int   s_nbr[NPB][MU + 1];        // 8.4 KB, padded
    const int tid   = threadIdx.x;
    const int node0 = blockIdx.x * NPB;

    // prologue: finish encode reduction; init tmax; stage neighbour lists
    if (tid < BATCH * NLAT) {
        float s = 0.0f;
        #pragma unroll
        for (int c = 0; c < NCHUNK; ++c) s += partial[tid * NCHUNK + c];
        s_enc[tid] = s + enc_b[tid % NLAT];
    }
    if (tid < NPB) s_tm[tid] = 0;
    {
        const int node = tid >> 3, ch = tid & 7;     // 512 int4 chunks
        int4 v = make_int4(0, 0, 0, 0);
        if (node0 + node < N_NODES)
            v = ((const int4*)(nbr + (size_t)(node0 + node) * MU))[ch];
        s_nbr[node][ch * 4 + 0] = v.x; s_nbr[node][ch * 4 + 1] = v.y;
        s_nbr[node][ch * 4 + 2] = v.z; s_nbr[node][ch * 4 + 3] = v.w;
    }
    __syncthreads();

    // ---- Phase A: coalesced bw loads, inv/tmax -> LDS
    {
        const int g    = tid >> 6;       // wave id 0..7
        const int lane = tid & 63;       // node
        const int p    = node0 + lane;
        if (p < N_NODES) {
            float tloc = 0.0f;
            for (int i = g; i < NLAT; i += 8) {
                float bwv[NLAT];
                #pragma unroll
                for (int k = 0; k < NLAT; ++k)
                    bwv[k] = bw[((size_t)(i * NLAT + k)) * N_NODES + p];
                float invv[BATCH];
                #pragma unroll
                for (int b = 0; b < BATCH; ++b) {
                    float z = 0.0f;
                    #pragma unroll
                    for (int k = 0; k < NLAT; ++k)
                        z = fmaf(s_enc[b * NLAT + k], bwv[k], z);
                    const float sg = 1.0f / (1.0f + __expf(-z));
                    const float t  = sg * (float)MU;
                    tloc = fmaxf(tloc, t);
                    invv[b] = __builtin_amdgcn_rcpf(t * t);
                }
                float4* dst = (float4*)&s_inv[i][lane][0];
                dst[0] = make_float4(invv[0], invv[1], invv[2], invv[3]);
                dst[1] = make_float4(invv[4], invv[5], invv[6], invv[7]);
            }
            atomicMax(&s_tm[lane], __float_as_int(tloc));  // t>0: bits ordered
        }
    }
    __syncthreads();

    // ---- Phase B: thread = (node, ipair); pairs 0..4 cover i = 0..9
    const int node  = tid >> 3;          // 0..63
    const int ipair = tid & 7;           // 0..7 (0..4 active)
    const int p     = node0 + node;
    const int i0    = 2 * ipair;
    const bool act  = (ipair < 5) && (p < N_NODES);

    v2f inv2[2][4], asum[2][4], ssum[2][4];
    #pragma unroll
    for (int ii = 0; ii < 2; ++ii)
        #pragma unroll
        for (int b2 = 0; b2 < 4; ++b2) {
            inv2[ii][b2] = (v2f){0.0f, 0.0f};
            asum[ii][b2] = (v2f){0.0f, 0.0f};
            ssum[ii][b2] = (v2f){0.0f, 0.0f};
        }
    int mcap = 0;
    if (act) {
        #pragma unroll
        for (int ii = 0; ii < 2; ++ii) {
            const float4* iv = (const float4*)&s_inv[i0 + ii][node][0];
            const float4 a = iv[0], c = iv[1];
            inv2[ii][0] = (v2f){a.x, a.y}; inv2[ii][1] = (v2f){a.z, a.w};
            inv2[ii][2] = (v2f){c.x, c.y}; inv2[ii][3] = (v2f){c.z, c.w};
        }
        mcap = min(MU, (int)__int_as_float(s_tm[node]) + 1);
    }

    for (int m = 0; m < mcap; ++m) {
        const int idx = s_nbr[node][m];             // 8 addrs, LDS broadcast
        const v2f g2 = *(const v2f*)(dec_t + (size_t)idx * DT_STRIDE + i0);
        const float m2 = (float)(m * m);
        const v2f nm2 = {-m2, -m2}, one = {1.0f, 1.0f};
        #pragma unroll
        for (int ii = 0; ii < 2; ++ii) {
            const v2f gg = {g2[ii], g2[ii]};
            #pragma unroll
            for (int b2 = 0; b2 < 4; ++b2) {
                const v2f win = v2_max0(v2_fma(nm2, inv2[ii][b2], one));
                ssum[ii][b2] += win;
                asum[ii][b2] = v2_fma(gg, win, asum[ii][b2]);
            }
        }
    }

    // epilogue: r[b] = this lane's 2-latent contribution; butterfly over the
    // 8-lane ipair group so every lane holds the full sum for each b.
    float r[BATCH];
    #pragma unroll
    for (int b2 = 0; b2 < 4; ++b2)
        #pragma unroll
        for (int h = 0; h < 2; ++h) {
            const int b = 2 * b2 + h;
            r[b] = act ? s_enc[b * NLAT + i0]     * asum[0][b2][h] *
                             __builtin_amdgcn_rcpf(ssum[0][b2][h]) +
                         s_enc[b * NLAT + i0 + 1] * asum[1][b2][h] *
                             __builtin_amdgcn_rcpf(ssum[1][b2][h])
                       : 0.0f;
        }
    #pragma unroll
    for (int mask = 1; mask < 8; mask <<= 1)
        #pragma unroll
        for (int b = 0; b < BATCH; ++b)
            r[b] += __shfl_xor(r[b], mask, 8);

    if (p < N_NODES)
        out[(size_t)ipair * N_NODES + p] = r[ipair];   // lane ipair -> batch ipair
}

extern "C" void kernel_launch(void* const* d_in, const int* in_sizes, int n_in,
                              void* d_out, int out_size, void* d_ws, size_t ws_size,
                              hipStream_t stream) {
    const float* x       = (const float*)d_in[0];   // [B, N]
    const float* enc_w   = (const float*)d_in[1];   // [n, N]
    const float* enc_b   = (const float*)d_in[2];   // [n]
    const float* decoder = (const float*)d_in[3];   // [n, N]
    const float* bwl     = (const float*)d_in[4];   // [n, n, N]
    const int*   nbr     = (const int*)d_in[5];     // [N, MU]
    float* out = (float*)d_out;                     // [B, N]

    float* partial = (float*)((char*)d_ws + 1024);   // 2000 floats
    float* dec_t   = (float*)((char*)d_ws + 65536);  // 3.2 MB

    encode_a_transpose<<<ENC_BLOCKS + TR_BLOCKS, 256, 0, stream>>>(
        x, enc_w, decoder, partial, dec_t);

    const int blocks = (N_NODES + NPB - 1) / NPB;   // 782
    nrbs_main_kernel<<<blocks, 512, 0, stream>>>(
        dec_t, bwl, nbr, partial, enc_b, out);
}